// Round 6
// baseline (204.062 us; speedup 1.0000x reference)
//
#include <hip/hip_runtime.h>
#include <math.h>

typedef __attribute__((ext_vector_type(8)))  short short8;
typedef __attribute__((ext_vector_type(16))) float float16_t;

__device__ __forceinline__ short f2bf(float f) {          // RNE (prep only)
    union { float f; unsigned u; } c; c.f = f;
    unsigned u = c.u + 0x7fffu + ((c.u >> 16) & 1u);
    return (short)(u >> 16);
}
__device__ __forceinline__ unsigned fbits(float f) {
    union { float f; unsigned u; } c; c.f = f; return c.u;
}
__device__ __forceinline__ float16_t zero16() {
    float16_t z;
#pragma unroll
    for (int r = 0; r < 16; ++r) z[r] = 0.0f;
    return z;
}

// ---------------------------------------------------------------------------
// Prep (fp32 in -> bf16 out):  (verbatim r0 / verified-172us version)
//   Qz  = cos(x[...,:8])*cos(theta)            -> bf16 [32768][8]
//   W1z = [W1 | b1 | 0...] K-padded 8->16      -> bf16 [2048][16]
//   W2P = W2 in 32x32x16 MFMA B-fragment order:
//         [ntile(16)][kstep(128)][lane(64)][8]
//         element = W2[ntile*32 + (lane&31)][kstep*16 + (lane>>5)*8 + j]
// ---------------------------------------------------------------------------
__global__ __launch_bounds__(256) void prep_kernel(
    const float* __restrict__ x, const float* __restrict__ theta,
    const float* __restrict__ W1, const float* __restrict__ b1,
    const float* __restrict__ W2,
    short* __restrict__ W2P, short* __restrict__ Qz, short* __restrict__ W1z)
{
    int gid = blockIdx.x * 256 + threadIdx.x;
    if (gid < 131072) {                       // W2P
        int lane = gid & 63;
        int ks   = (gid >> 6) & 127;
        int nt   = gid >> 13;
        int n = nt * 32 + (lane & 31);
        int k = ks * 16 + (lane >> 5) * 8;
        const float4* p = (const float4*)(W2 + n * 2048 + k);
        float4 v0 = p[0], v1 = p[1];
        short8 o;
        o[0] = f2bf(v0.x); o[1] = f2bf(v0.y); o[2] = f2bf(v0.z); o[3] = f2bf(v0.w);
        o[4] = f2bf(v1.x); o[5] = f2bf(v1.y); o[6] = f2bf(v1.z); o[7] = f2bf(v1.w);
        *(short8*)(W2P + gid * 8) = o;
    } else if (gid < 131072 + 32768) {        // Qz
        int t = gid - 131072;
        const float4* xp = (const float4*)(x + t * 512);
        float4 x0 = xp[0], x1 = xp[1];
        float xv[8] = {x0.x, x0.y, x0.z, x0.w, x1.x, x1.y, x1.z, x1.w};
        short8 q;
#pragma unroll
        for (int c = 0; c < 8; ++c)
            q[c] = f2bf(cosf(xv[c]) * cosf(theta[c]));
        *(short8*)(Qz + t * 8) = q;
    } else if (gid < 131072 + 32768 + 2048) { // W1z rows: [W1(8) | b1 | 0x7]
        int f = gid - (131072 + 32768);
        const float4* wp = (const float4*)(W1 + f * 8);
        float4 w0 = wp[0], w1 = wp[1];
        short8 wv;
        wv[0] = f2bf(w0.x); wv[1] = f2bf(w0.y); wv[2] = f2bf(w0.z); wv[3] = f2bf(w0.w);
        wv[4] = f2bf(w1.x); wv[5] = f2bf(w1.y); wv[6] = f2bf(w1.z); wv[7] = f2bf(w1.w);
        short8 bz = {0,0,0,0,0,0,0,0};
        bz[0] = f2bf(b1[f]);                  // k=8 slot carries the bias
        *(short8*)(W1z + f * 16) = wv;
        *(short8*)(W1z + f * 16 + 8) = bz;
    }
}

// ---------------------------------------------------------------------------
// Fused FFN v4 — LDS-FREE, BARRIER-FREE.
// Each wave independently owns a 32m x 128n output tile. Per kt (BK=64):
//   stage1: d1a/d1b = mfma(W1 rows fh={0,1}, q)      (2 MFMA, C=0)
//           d1 lane (l31,lh) holds H[f=fh*32+4lh+8g+r][m=l31]  (m == l31!)
//   stage2 A-frag af(ks) needs lane (l31,lh): H[f=ks*16+lh*8+j][m=l31]
//     -> j0..3: quad g=2(ks&1)+lh from lane-half src lh=0
//        j4..7: same quad from lane-half src lh=1
//     i.e. own quad + lane^32 partner's quad of the SAME (fh=ks>>1, G).
//   The exchange is one __shfl_xor(...,32) per packed word: zero LDS,
//   zero __syncthreads, waves never synchronize. Stage-2: 16 MFMA into
//   acc[4] (64 AGPR). Stage-1 is duplicated across the 4 n-blocks
//   (12.5% extra MFMA) -- the price for removing every sync stall.
// Grid: 256 m-blocks x 4 n-blocks = 1024 blocks x 256 thr (4 indep waves).
// ---------------------------------------------------------------------------
__global__ __launch_bounds__(256, 2) void ffn_kernel(
    const short* __restrict__ Qz, const short* __restrict__ W1z,
    const short* __restrict__ W2P, const float* __restrict__ b2,
    float* __restrict__ out)
{
    const int tid  = threadIdx.x;
    const int lane = tid & 63;
    const int w    = tid >> 6;                 // wave 0..3 (independent)
    const int l31 = lane & 31, lh = lane >> 5;
    const int bid = blockIdx.x;
    const int nb = bid & 3, mb = bid >> 2;     // 4 n-blocks x 256 m-blocks
    const int m0 = mb * 128 + w * 32;          // this wave's 32 m-rows
    const int n0 = nb * 128;                   // this wave's 128 n-cols

    // stage-1 B operand: q rows (k 0..7) for lh=0; k=8 -> 1.0 for bias row
    short8 qf = {0,0,0,0,0,0,0,0};
    if (lh == 0)
        qf = *(const short8*)(Qz + (m0 + l31) * 8);
    else
        qf[0] = (short)0x3F80;                 // bf16(1.0)

    // loop-invariant lane offsets (short units)
    int w2off[4];
#pragma unroll
    for (int j = 0; j < 4; ++j)
        w2off[j] = (nb * 4 + j) * 65536 + lane * 8;
    const int a1off = l31 * 16 + lh * 8;       // within a 32-f row group

    float16_t acc[4];
#pragma unroll
    for (int j = 0; j < 4; ++j) acc[j] = zero16();

    // ---- prologue: a1 for kt=0 (consumed now) and kt=1 (carried) ----
    short8 a1c0 = *(const short8*)(W1z + a1off);           // kt0, f 0..31
    short8 a1c1 = *(const short8*)(W1z + 512 + a1off);     // kt0, f 32..63
    short8 a1n0 = *(const short8*)(W1z + 1024 + a1off);    // kt1
    short8 a1n1 = *(const short8*)(W1z + 1536 + a1off);
    float16_t d1a = __builtin_amdgcn_mfma_f32_32x32x16_bf16(a1c0, qf, zero16(), 0, 0, 0);
    float16_t d1b = __builtin_amdgcn_mfma_f32_32x32x16_bf16(a1c1, qf, zero16(), 0, 0, 0);

    const short* W2Pk = W2P;                   // advanced 2048/iter (= 4 ksteps)
    const short* W1za = W1z + 2048;            // a1 rows for kt+2, 1024/iter

    for (int kt = 0; kt < 32; ++kt) {
        // issue this kt's 16 B-fragments early (T14: issue-early, use-late;
        // no barrier ever drains them -- counted vmcnt at first use)
        short8 bfv[4][4];
#pragma unroll
        for (int ks = 0; ks < 4; ++ks)
#pragma unroll
            for (int j = 0; j < 4; ++j)
                bfv[ks][j] = *(const short8*)(W2Pk + w2off[j] + ks * 512);

        // ---- relu + truncation-pack H (kt) to bf16 words ----
        // Pw[fh][g][w] packs f = fh*32 + 4*lh + 8g + {2w, 2w+1}
        unsigned Pw[2][4][2];
#pragma unroll
        for (int g = 0; g < 4; ++g) {
            float a0 = fmaxf(d1a[g * 4 + 0], 0.0f);
            float a1 = fmaxf(d1a[g * 4 + 1], 0.0f);
            float a2 = fmaxf(d1a[g * 4 + 2], 0.0f);
            float a3 = fmaxf(d1a[g * 4 + 3], 0.0f);
            Pw[0][g][0] = __builtin_amdgcn_perm(fbits(a1), fbits(a0), 0x07060302u);
            Pw[0][g][1] = __builtin_amdgcn_perm(fbits(a3), fbits(a2), 0x07060302u);
            float b0 = fmaxf(d1b[g * 4 + 0], 0.0f);
            float b1 = fmaxf(d1b[g * 4 + 1], 0.0f);
            float b2v = fmaxf(d1b[g * 4 + 2], 0.0f);
            float b3 = fmaxf(d1b[g * 4 + 3], 0.0f);
            Pw[1][g][0] = __builtin_amdgcn_perm(fbits(b1), fbits(b0), 0x07060302u);
            Pw[1][g][1] = __builtin_amdgcn_perm(fbits(b3), fbits(b2v), 0x07060302u);
        }

        // ---- cross-half exchange -> A-fragments af[ks] ----
        short8 af[4];
#pragma unroll
        for (int ks = 0; ks < 4; ++ks) {
            const int fh = ks >> 1, e = (ks & 1) * 2;     // G_even = e, G_odd = e+1
            // own quad at MY G = e + lh
            unsigned v1w0 = lh ? Pw[fh][e + 1][0] : Pw[fh][e][0];
            unsigned v1w1 = lh ? Pw[fh][e + 1][1] : Pw[fh][e][1];
            // quad my PARTNER needs (partner's G), sent via shfl_xor 32
            unsigned wxw0 = lh ? Pw[fh][e][0] : Pw[fh][e + 1][0];
            unsigned wxw1 = lh ? Pw[fh][e][1] : Pw[fh][e + 1][1];
            unsigned p0 = (unsigned)__shfl_xor((int)wxw0, 32, 64);
            unsigned p1 = (unsigned)__shfl_xor((int)wxw1, 32, 64);
            union { int4 i4; short8 s8; } u;
            u.i4.x = (int)(lh ? p0 : v1w0);    // j0..1  (f src-half 0)
            u.i4.y = (int)(lh ? p1 : v1w1);    // j2..3
            u.i4.z = (int)(lh ? v1w0 : p0);    // j4..5  (f src-half 1)
            u.i4.w = (int)(lh ? v1w1 : p1);    // j6..7
            af[ks] = u.s8;
        }

        // ---- stage-1 MFMAs for kt+1 (issue ahead of stage-2 burst) ----
        if (kt < 31) {
            d1a = __builtin_amdgcn_mfma_f32_32x32x16_bf16(a1n0, qf, zero16(), 0, 0, 0);
            d1b = __builtin_amdgcn_mfma_f32_32x32x16_bf16(a1n1, qf, zero16(), 0, 0, 0);
        }
        if (kt < 30) {
            a1n0 = *(const short8*)(W1za + a1off);         // kt+2
            a1n1 = *(const short8*)(W1za + 512 + a1off);
        }
        W1za += 1024;

        // ---- stage-2: 16 MFMA ----
#pragma unroll
        for (int ks = 0; ks < 4; ++ks)
#pragma unroll
            for (int j = 0; j < 4; ++j)
                acc[j] = __builtin_amdgcn_mfma_f32_32x32x16_bf16(
                    af[ks], bfv[ks][j], acc[j], 0, 0, 0);

        W2Pk += 2048;
    }

    // ---- epilogue: out(fp32) = acc + b2 ----
#pragma unroll
    for (int j = 0; j < 4; ++j) {
        const int n = n0 + j * 32 + l31;
        const float b2v = b2[n];
        const int base = (m0 + 4 * lh) * 512 + n;
#pragma unroll
        for (int r = 0; r < 16; ++r) {
            const int off = ((r & 3) + 8 * (r >> 2)) * 512;
            out[base + off] = acc[j][r] + b2v;
        }
    }
}

// ---------------------------------------------------------------------------
extern "C" void kernel_launch(void* const* d_in, const int* in_sizes, int n_in,
                              void* d_out, int out_size, void* d_ws, size_t ws_size,
                              hipStream_t stream)
{
    const float* x     = (const float*)d_in[0];  // [8,4096,512] fp32
    const float* theta = (const float*)d_in[1];  // [8] fp32
    const float* W1    = (const float*)d_in[2];  // [2048,8] fp32
    const float* b1    = (const float*)d_in[3];  // [2048] fp32
    const float* W2    = (const float*)d_in[4];  // [512,2048] fp32
    const float* b2    = (const float*)d_in[5];  // [512] fp32
    float* out = (float*)d_out;                  // [8,4096,512] fp32

    short* W2P = (short*)d_ws;                          // 2 MB
    short* Qz  = (short*)((char*)d_ws + 2097152);       // 512 KB
    short* W1z = (short*)((char*)d_ws + 2621440);       // 64 KB

    prep_kernel<<<648, 256, 0, stream>>>(x, theta, W1, b1, W2, W2P, Qz, W1z);
    ffn_kernel<<<1024, 256, 0, stream>>>(Qz, W1z, W2P, b2, out);
}

// Round 7
// 181.529 us; speedup vs baseline: 1.1241x; 1.1241x over previous
//
#include <hip/hip_runtime.h>
#include <math.h>

typedef __attribute__((ext_vector_type(8)))  short short8;
typedef __attribute__((ext_vector_type(16))) float float16_t;

__device__ __forceinline__ short f2bf(float f) {          // RNE (prep only)
    union { float f; unsigned u; } c; c.f = f;
    unsigned u = c.u + 0x7fffu + ((c.u >> 16) & 1u);
    return (short)(u >> 16);
}
__device__ __forceinline__ unsigned fbits(float f) {
    union { float f; unsigned u; } c; c.f = f; return c.u;
}
__device__ __forceinline__ float16_t zero16() {
    float16_t z;
#pragma unroll
    for (int r = 0; r < 16; ++r) z[r] = 0.0f;
    return z;
}

// ---------------------------------------------------------------------------
// Prep, split into two kernels (mappings verbatim from the verified r0 prep;
// split is free and lets rocprof attribute prep time by name).
//   W2P = W2 in 32x32x16 MFMA B-fragment order:
//         [ntile(16)][kstep(128)][lane(64)][8]
//         element = W2[ntile*32 + (lane&31)][kstep*16 + (lane>>5)*8 + j]
// ---------------------------------------------------------------------------
__global__ __launch_bounds__(256) void prep_w2p(
    const float* __restrict__ W2, short* __restrict__ W2P)
{
    int gid = blockIdx.x * 256 + threadIdx.x;     // 0..131071
    int lane = gid & 63;
    int ks   = (gid >> 6) & 127;
    int nt   = gid >> 13;
    int n = nt * 32 + (lane & 31);
    int k = ks * 16 + (lane >> 5) * 8;
    const float4* p = (const float4*)(W2 + n * 2048 + k);
    float4 v0 = p[0], v1 = p[1];
    short8 o;
    o[0] = f2bf(v0.x); o[1] = f2bf(v0.y); o[2] = f2bf(v0.z); o[3] = f2bf(v0.w);
    o[4] = f2bf(v1.x); o[5] = f2bf(v1.y); o[6] = f2bf(v1.z); o[7] = f2bf(v1.w);
    *(short8*)(W2P + gid * 8) = o;
}

//   Qz  = cos(x[...,:8])*cos(theta)            -> bf16 [32768][8]
//   W1z = [W1 | b1 | 0...] K-padded 8->16      -> bf16 [2048][16]
//         (col 8 = b1[f]; ffn sets Q's k=8 input to 1.0 so MFMA adds bias)
__global__ __launch_bounds__(256) void prep_small(
    const float* __restrict__ x, const float* __restrict__ theta,
    const float* __restrict__ W1, const float* __restrict__ b1,
    short* __restrict__ Qz, short* __restrict__ W1z)
{
    int gid = blockIdx.x * 256 + threadIdx.x;     // 0..34815
    if (gid < 32768) {                            // Qz
        int t = gid;
        const float4* xp = (const float4*)(x + t * 512);
        float4 x0 = xp[0], x1 = xp[1];
        float xv[8] = {x0.x, x0.y, x0.z, x0.w, x1.x, x1.y, x1.z, x1.w};
        short8 q;
#pragma unroll
        for (int c = 0; c < 8; ++c)
            q[c] = f2bf(cosf(xv[c]) * cosf(theta[c]));
        *(short8*)(Qz + t * 8) = q;
    } else {                                      // W1z rows: [W1(8) | b1 | 0x7]
        int f = gid - 32768;
        const float4* wp = (const float4*)(W1 + f * 8);
        float4 w0 = wp[0], w1 = wp[1];
        short8 wv;
        wv[0] = f2bf(w0.x); wv[1] = f2bf(w0.y); wv[2] = f2bf(w0.z); wv[3] = f2bf(w0.w);
        wv[4] = f2bf(w1.x); wv[5] = f2bf(w1.y); wv[6] = f2bf(w1.z); wv[7] = f2bf(w1.w);
        short8 bz = {0,0,0,0,0,0,0,0};
        bz[0] = f2bf(b1[f]);                      // k=8 slot carries the bias
        *(short8*)(W1z + f * 16) = wv;
        *(short8*)(W1z + f * 16 + 8) = bz;
    }
}

// ---------------------------------------------------------------------------
// Stage 1: H^T tile (64 f x 128 m) for one K-tile. Bias comes in via the
// k=8 MFMA slot; epilogue is relu + truncation-pack (v_perm) + b64 LDS write.
// (Verbatim from the verified 77.9us kernel.)
// ---------------------------------------------------------------------------
__device__ __forceinline__ void stage1_tile(
    short8 a1, const short8* qf, short* __restrict__ dst,
    int wx, int wy, int lh, int l31)
{
#pragma unroll
    for (int i = 0; i < 2; ++i) {
        float16_t d1 = __builtin_amdgcn_mfma_f32_32x32x16_bf16(
            a1, qf[i], zero16(), 0, 0, 0);
        const int m = wy * 64 + i * 32 + l31;        // C/D col = m
#pragma unroll
        for (int g = 0; g < 4; ++g) {                // rows f = wx*32+4lh+8g+r
            float v0 = fmaxf(d1[g * 4 + 0], 0.0f);
            float v1 = fmaxf(d1[g * 4 + 1], 0.0f);
            float v2 = fmaxf(d1[g * 4 + 2], 0.0f);
            float v3 = fmaxf(d1[g * 4 + 3], 0.0f);
            uint2 pp;                                 // truncation bf16 pack
            pp.x = __builtin_amdgcn_perm(fbits(v1), fbits(v0), 0x07060302u);
            pp.y = __builtin_amdgcn_perm(fbits(v3), fbits(v2), 0x07060302u);
            *(uint2*)(dst + (wx * 4 + g) * 1024 + m * 8 + 4 * lh) = pp;
        }
    }
}

// ---------------------------------------------------------------------------
// Fused FFN v5: r0's proven per-iter work, 4-buffer LDS pipeline with
// write-ahead distance 2 -> __syncthreads only every SECOND kt (16 vs 32).
// Hazard proof (barrier after odd kt; concurrent window = {2j, 2j+1}):
//   reads in window: bufs {2j, 2j+1} % 4 ; writes: bufs {2j+2, 2j+3} % 4
//     -> disjoint, no intra-window race.
//   RAW: consumer kt needs H(kt) written at kt-2; a barrier (end of kt-1 or
//     kt-2, whichever is odd) separates them.
//   WAR: writer kt reuses buf (kt+2)%4 last read at kt-2; same barrier
//     separates.
// Per-iter work, registers (128 VGPR + 128 AGPR, 2 waves/SIMD), B-prefetch
// pipeline, and numerics are identical to the 77.9us kernel. LDS 64KB,
// 2 blocks/CU (VGPR-limited, unchanged).
// ---------------------------------------------------------------------------
__global__ __launch_bounds__(256, 2) void ffn_kernel(
    const short* __restrict__ Qz, const short* __restrict__ W1z,
    const short* __restrict__ W2P, const float* __restrict__ b2,
    float* __restrict__ out)
{
    __shared__ short Hs[4 * 8192];            // 4 x 16KB rotating buffers

    const int tid  = threadIdx.x;
    const int lane = tid & 63;
    const int w    = tid >> 6;                 // wave 0..3
    const int wy = w & 1, wx = w >> 1;         // m-half (64), n-half (128)
    const int l31 = lane & 31, lh = lane >> 5;
    const int bid = blockIdx.x;
    const int nt = bid & 1, mt = bid >> 1;
    const int m0 = mt * 128, n0 = nt * 256;

    // stage-1 B operand: Q rows (k 0..7) for lh=0; k=8 -> 1.0 for bias row
    short8 qf[2];
#pragma unroll
    for (int i = 0; i < 2; ++i) {
        short8 v = {0,0,0,0,0,0,0,0};
        if (lh == 0)
            v = *(const short8*)(Qz + (m0 + wy * 64 + i * 32 + l31) * 8);
        else
            v[0] = (short)0x3F80;              // bf16(1.0)
        qf[i] = v;
    }

    // loop-invariant lane offsets (short units)
    int w2off[4];
#pragma unroll
    for (int j = 0; j < 4; ++j)
        w2off[j] = (nt * 8 + wx * 4 + j) * 65536 + lane * 8;
    const int a1off = (wx * 32 + l31) * 16 + lh * 8;

    float16_t acc[2][4];
#pragma unroll
    for (int i = 0; i < 2; ++i)
#pragma unroll
        for (int j = 0; j < 4; ++j) acc[i][j] = zero16();

    // ---- prologue: produce H(0) and H(1); preload a1 for H(2) ----
    const short* W2Pk = W2P;                   // advanced 2048/iter (= 1 kt)

    short8 bfvA[2][4], bfvB[2][4];
#pragma unroll
    for (int ks = 0; ks < 2; ++ks)
#pragma unroll
        for (int j = 0; j < 4; ++j)
            bfvA[ks][j] = *(const short8*)(W2Pk + w2off[j] + ks * 512);
    {
        short8 a1_0 = *(const short8*)(W1z + a1off);          // H(0)
        short8 a1_1 = *(const short8*)(W1z + 1024 + a1off);   // H(1)
        stage1_tile(a1_0, qf, Hs,        wx, wy, lh, l31);
        stage1_tile(a1_1, qf, Hs + 8192, wx, wy, lh, l31);
    }
    short8 a1n = *(const short8*)(W1z + 2048 + a1off);        // for H(2)
    const short* W1za = W1z + 3 * 1024;        // fetch target: H(kt+3)
    __syncthreads();

    for (int kt = 0; kt < 32; ++kt) {
        const short* rd = Hs + (kt & 3) * 8192;        // consume H(kt)
        short* wr = Hs + ((kt + 2) & 3) * 8192;        // produce H(kt+2)

        // issue B(kt, ks 2..3) now; consumed after 16 MFMAs of shadow
#pragma unroll
        for (int ks = 0; ks < 2; ++ks)
#pragma unroll
            for (int j = 0; j < 4; ++j)
                bfvB[ks][j] = *(const short8*)(W2Pk + w2off[j] + (ks + 2) * 512);

        // stage 1 for kt+2 (a1 already in registers -> starts immediately)
        if (kt < 30)
            stage1_tile(a1n, qf, wr, wx, wy, lh, l31);
        if (kt < 29)
            a1n = *(const short8*)(W1za + a1off);      // W1 rows for H(kt+3)
        W1za += 1024;

        // stage 2, phase A: ks 0..1 with prefetched bfvA
#pragma unroll
        for (int ks = 0; ks < 2; ++ks) {
            short8 af[2];
#pragma unroll
            for (int i = 0; i < 2; ++i)
                af[i] = *(const short8*)(rd + (ks * 2 + lh) * 1024 +
                                         (wy * 64 + i * 32 + l31) * 8);
#pragma unroll
            for (int i = 0; i < 2; ++i)
#pragma unroll
                for (int j = 0; j < 4; ++j)
                    acc[i][j] = __builtin_amdgcn_mfma_f32_32x32x16_bf16(
                        af[i], bfvA[ks][j], acc[i][j], 0, 0, 0);
        }

        // prefetch B(kt+1, ks 0..1) (bfvA regs now free)
        W2Pk += 2048;
        if (kt < 31) {
#pragma unroll
            for (int ks = 0; ks < 2; ++ks)
#pragma unroll
                for (int j = 0; j < 4; ++j)
                    bfvA[ks][j] = *(const short8*)(W2Pk + w2off[j] + ks * 512);
        }

        // stage 2, phase B: ks 2..3 with bfvB
#pragma unroll
        for (int ks = 0; ks < 2; ++ks) {
            short8 af[2];
#pragma unroll
            for (int i = 0; i < 2; ++i)
                af[i] = *(const short8*)(rd + ((ks + 2) * 2 + lh) * 1024 +
                                         (wy * 64 + i * 32 + l31) * 8);
#pragma unroll
            for (int i = 0; i < 2; ++i)
#pragma unroll
                for (int j = 0; j < 4; ++j)
                    acc[i][j] = __builtin_amdgcn_mfma_f32_32x32x16_bf16(
                        af[i], bfvB[ks][j], acc[i][j], 0, 0, 0);
        }

        if (kt & 1)                            // rendezvous every 2nd kt
            __syncthreads();
    }

    // ---- epilogue: out(fp32) = acc + b2 ----
#pragma unroll
    for (int j = 0; j < 4; ++j) {
        const int n = n0 + wx * 128 + j * 32 + l31;
        const float b2v = b2[n];
#pragma unroll
        for (int i = 0; i < 2; ++i) {
            const int base = (m0 + wy * 64 + i * 32 + 4 * lh) * 512 + n;
#pragma unroll
            for (int r = 0; r < 16; ++r) {
                const int off = ((r & 3) + 8 * (r >> 2)) * 512;
                out[base + off] = acc[i][j][r] + b2v;
            }
        }
    }
}

// ---------------------------------------------------------------------------
extern "C" void kernel_launch(void* const* d_in, const int* in_sizes, int n_in,
                              void* d_out, int out_size, void* d_ws, size_t ws_size,
                              hipStream_t stream)
{
    const float* x     = (const float*)d_in[0];  // [8,4096,512] fp32
    const float* theta = (const float*)d_in[1];  // [8] fp32
    const float* W1    = (const float*)d_in[2];  // [2048,8] fp32
    const float* b1    = (const float*)d_in[3];  // [2048] fp32
    const float* W2    = (const float*)d_in[4];  // [512,2048] fp32
    const float* b2    = (const float*)d_in[5];  // [512] fp32
    float* out = (float*)d_out;                  // [8,4096,512] fp32

    short* W2P = (short*)d_ws;                          // 2 MB
    short* Qz  = (short*)((char*)d_ws + 2097152);       // 512 KB
    short* W1z = (short*)((char*)d_ws + 2621440);       // 64 KB

    prep_w2p<<<512, 256, 0, stream>>>(W2, W2P);
    prep_small<<<136, 256, 0, stream>>>(x, theta, W1, b1, Qz, W1z);
    ffn_kernel<<<512, 256, 0, stream>>>(Qz, W1z, W2P, b2, out);
}